// Round 3
// baseline (451.612 us; speedup 1.0000x reference)
//
#include <hip/hip_runtime.h>

// SelfAttention: B=4, S=2048, D=1024, fp32 in/out.
// q=x@Wq^T+bq, k=..., v=...; out = softmax(q k^T) @ v   (no 1/sqrt(d) scale)
//
// Precision plan: main terms in bf16 MFMA (hi parts), correction terms
// (hi*lo + lo*full) in exact-integer i8 MFMA (16x16x64, 2x rate). Symmetric
// quant ranges make both cross terms share one scale -> one i32 acc set.
//   q/k proj:  x*W  = xh*Wh  [bf16] + (xh*Wl + xl*W)   [i8]   (2+2 per K-64)
//   scores:    q*k  = qh*kh  [bf16] + (qh*kl + ql*k)   [i8]
// v projection: single bf16 term (dv ~1.6e-3 harmless). PV in f16.

#define Bb 4
#define Ss 2048
#define Dd 1024
#define Mtot 8192  // B*S

typedef __bf16 bf16x8 __attribute__((ext_vector_type(8)));
typedef _Float16 f16x8 __attribute__((ext_vector_type(8)));
typedef float f32x4 __attribute__((ext_vector_type(4)));
typedef int i32x4 __attribute__((ext_vector_type(4)));
typedef unsigned short u16;
typedef unsigned int u32;
typedef unsigned char u8;
typedef u16 u16x8 __attribute__((ext_vector_type(8)));
typedef u16 u16x4 __attribute__((ext_vector_type(4)));
typedef void __attribute__((address_space(1))) gvoid_t;
typedef void __attribute__((address_space(3))) svoid_t;

// quant ranges: x/q/k hi: +-8 ; lo digits: +-0.015625 (=half-ulp of bf16 at 8)
// W full: +-0.25 ; Wl: +-4.8828125e-4. Scale products match by construction.
#define PS_QKV (3.90625e-3f / 16129.0f)   // (8/127)*(4.8828125e-4/127)
#define PS_SCORE (0.125f / 16129.0f)      // (8/127)*(0.015625/127)
#define INV_HI 15.875f                    // 127/8
#define INV_LO 8128.0f                    // 127/0.015625
#define INV_W 508.0f                      // 127/0.25
#define INV_WL 260096.0f                  // 127/4.8828125e-4

__device__ __forceinline__ void gl_lds16(const void* g, void* l) {
  __builtin_amdgcn_global_load_lds((gvoid_t*)g, (svoid_t*)l, 16, 0, 0);
}

__device__ __forceinline__ u16 f2bf(float f) {  // RNE float->bf16
  u32 u = __builtin_bit_cast(u32, f);
  u = (u + 0x7FFFu + ((u >> 16) & 1u)) >> 16;
  return (u16)u;
}
__device__ __forceinline__ float bf2f(u16 h) {
  u32 u = ((u32)h) << 16;
  return __builtin_bit_cast(float, u);
}
__device__ __forceinline__ u16 f2h(float f) {
  return __builtin_bit_cast(u16, (_Float16)f);
}
__device__ __forceinline__ bf16x8 frag_ld(const char* p) {
  u16x8 v = *(const u16x8*)p;
  return __builtin_bit_cast(bf16x8, v);
}
__device__ __forceinline__ f16x8 frag_ld_h(const char* p) {
  u16x8 v = *(const u16x8*)p;
  return __builtin_bit_cast(f16x8, v);
}
__device__ __forceinline__ int clamp_i8(float v, float inv) {
  float t = v * inv;
  t = fminf(fmaxf(t, -127.f), 127.f);
  return __float2int_rn(t);
}
__device__ __forceinline__ u32 pack4(const float* v, float inv) {
  u32 r = 0;
#pragma unroll
  for (int j = 0; j < 4; ++j) r |= ((u32)(clamp_i8(v[j], inv) & 255)) << (8 * j);
  return r;
}

__device__ __forceinline__ f32x4 mfma_bf16(bf16x8 a, bf16x8 b, f32x4 c) {
  return __builtin_amdgcn_mfma_f32_16x16x32_bf16(a, b, c, 0, 0, 0);
}
__device__ __forceinline__ i32x4 mfma_i8(i32x4 a, i32x4 b, i32x4 c) {
  return __builtin_amdgcn_mfma_i32_16x16x64_i8(a, b, c, 0, 0, 0);
}

// stage a tile with 64-byte rows (K-32 bf16 chunk or K-64 i8 chunk) to LDS.
// ROUNDS*4 KB total; LDS layout linear, row-major, 64 B/row.
template <int ROUNDS>
__device__ __forceinline__ void stageT(const char* g, long row0, long ldb,
                                       long k0b, char* l, int tid) {
#pragma unroll
  for (int r = 0; r < ROUNDS; ++r) {
    int o = r * 4096 + tid * 16;
    int row = o >> 6;
    int col = o & 63;
    gl_lds16(g + (row0 + row) * ldb + k0b + col, l + o);
  }
}

// legacy helper for pv_gemm (128x32 f16 tile, 8 KB)
__device__ __forceinline__ void stage8k(const u16* gbase, long row0, int k0, int ld,
                                        char* lds, int tid) {
  const char* gb = (const char*)gbase;
#pragma unroll
  for (int it = 0; it < 2; ++it) {
    int o = it * 4096 + tid * 16;
    int row = o >> 6;
    int colb = o & 63;
    gl_lds16(gb + ((row0 + row) * (long)ld + k0) * 2 + colb, lds + o);
  }
}

// ---------------------------------------------------------------- converts
// blocks [0,8192): x   [8192,9216): Wq   [9216,10240): Wk   [10240,11264): Wv
// x: writes xh bf16 + i8(xh) + i8(xl).  W: writes Wh bf16 + i8(W) + i8(Wl).
__global__ void __launch_bounds__(256) convert_all(
    const float* __restrict__ x, const float* __restrict__ Wq,
    const float* __restrict__ Wk, const float* __restrict__ Wv,
    u16* __restrict__ xh, u8* __restrict__ xh_i8, u8* __restrict__ xl_i8,
    u16* __restrict__ wqh, u8* __restrict__ wq_i8, u8* __restrict__ wql_i8,
    u16* __restrict__ wkh, u8* __restrict__ wk_i8, u8* __restrict__ wkl_i8,
    u16* __restrict__ wvh, u8* __restrict__ wv_i8, u8* __restrict__ wvl_i8) {
  long b = blockIdx.x;
  const float* src;
  u16* hb;
  u8 *d0, *d1;
  float inv0, inv1;
  bool d0_is_hi;
  long i;
  if (b < 8192) {
    src = x; hb = xh; d0 = xh_i8; d1 = xl_i8;
    inv0 = INV_HI; inv1 = INV_LO; d0_is_hi = true;
    i = b * 256 + threadIdx.x;
  } else {
    int w = (int)((b - 8192) >> 10);
    src = (w == 0) ? Wq : (w == 1) ? Wk : Wv;
    hb = (w == 0) ? wqh : (w == 1) ? wkh : wvh;
    d0 = (w == 0) ? wq_i8 : (w == 1) ? wk_i8 : wv_i8;
    d1 = (w == 0) ? wql_i8 : (w == 1) ? wkl_i8 : wvl_i8;
    inv0 = INV_W; inv1 = INV_WL; d0_is_hi = false;
    i = ((b - 8192) & 1023) * 256 + threadIdx.x;
  }
  f32x4 v = ((const f32x4*)src)[i];
  u16x4 h;
  float hi_f[4], lo_f[4], full_f[4];
#pragma unroll
  for (int j = 0; j < 4; ++j) {
    u16 hh = f2bf(v[j]);
    h[j] = hh;
    hi_f[j] = bf2f(hh);
    lo_f[j] = v[j] - hi_f[j];
    full_f[j] = v[j];
  }
  ((u16x4*)hb)[i] = h;
  ((u32*)d0)[i] = pack4(d0_is_hi ? hi_f : full_f, inv0);
  ((u32*)d1)[i] = pack4(lo_f, inv1);
}

// ---------------------------------------------------------------- QKV GEMM
// block-tile 128m x 64n, 4 waves (2x2), wave-tile 64x32 (4mt x 2nt).
// z=0: q (bf16 hi + i8 digits out), z=1: k (bf16 hi + i8 digits), z=2: v (f16, transposed)
// LDS map (48 KB): 0 xh-klo | 8K xh-khi | 16K xh_i8 | 24K xl_i8
//                  32K Wh-klo | 36K Wh-khi | 40K W_i8 | 44K Wl_i8
__global__ void __launch_bounds__(256) qkv_gemm(
    const u16* __restrict__ xh, const u8* __restrict__ xh_i8, const u8* __restrict__ xl_i8,
    const u16* __restrict__ wqh, const u8* __restrict__ wq_i8, const u8* __restrict__ wql_i8,
    const u16* __restrict__ wkh, const u8* __restrict__ wk_i8, const u8* __restrict__ wkl_i8,
    const u16* __restrict__ wvh,
    const float* __restrict__ bq, const float* __restrict__ bk, const float* __restrict__ bv,
    u16* __restrict__ qh, u8* __restrict__ qh_i8, u8* __restrict__ ql_i8,
    u16* __restrict__ kh, u8* __restrict__ k_i8, u8* __restrict__ kl_i8,
    u16* __restrict__ vt) {
  __shared__ char lds[49152];
  const int tid = threadIdx.x;
  const int z = blockIdx.z;
  const long m0 = (long)blockIdx.y * 128;
  const int n0 = blockIdx.x * 64;
  const int wave = tid >> 6, lane = tid & 63;
  const int wm = wave >> 1, wn = wave & 1;
  const int lr = lane & 15, lk = lane >> 4;

  const u16* wh = (z == 0) ? wqh : (z == 1) ? wkh : wvh;
  const u8* w0 = (z == 0) ? wq_i8 : wk_i8;
  const u8* w1 = (z == 0) ? wql_i8 : wkl_i8;
  const float* bias = (z == 0) ? bq : (z == 1) ? bk : bv;

  f32x4 accf[4][2] = {};
  i32x4 acci[4][2] = {};
  const char* xhc = (const char*)xh;
  const char* whc = (const char*)wh;

  for (int k0 = 0; k0 < Dd; k0 += 64) {
    stageT<2>(xhc, m0, 2048, 2 * k0, lds + 0, tid);
    stageT<2>(xhc, m0, 2048, 2 * k0 + 64, lds + 8192, tid);
    stageT<1>(whc, n0, 2048, 2 * k0, lds + 32768, tid);
    stageT<1>(whc, n0, 2048, 2 * k0 + 64, lds + 36864, tid);
    if (z < 2) {
      stageT<2>((const char*)xh_i8, m0, 1024, k0, lds + 16384, tid);
      stageT<2>((const char*)xl_i8, m0, 1024, k0, lds + 24576, tid);
      stageT<1>((const char*)w0, n0, 1024, k0, lds + 40960, tid);
      stageT<1>((const char*)w1, n0, 1024, k0, lds + 45056, tid);
    }
    __syncthreads();
    bf16x8 bh[2][2];
    i32x4 bw[2], bwl[2];
#pragma unroll
    for (int nt = 0; nt < 2; ++nt) {
      int rb = (wn * 32 + nt * 16 + lr) * 64 + lk * 16;
      bh[nt][0] = frag_ld(lds + 32768 + rb);
      bh[nt][1] = frag_ld(lds + 36864 + rb);
      if (z < 2) {
        bw[nt] = *(const i32x4*)(lds + 40960 + rb);
        bwl[nt] = *(const i32x4*)(lds + 45056 + rb);
      }
    }
#pragma unroll
    for (int mt = 0; mt < 4; ++mt) {
      int ra = (wm * 64 + mt * 16 + lr) * 64 + lk * 16;
      bf16x8 a0 = frag_ld(lds + 0 + ra);
      bf16x8 a1 = frag_ld(lds + 8192 + ra);
#pragma unroll
      for (int nt = 0; nt < 2; ++nt) {
        accf[mt][nt] = mfma_bf16(a0, bh[nt][0], accf[mt][nt]);
        accf[mt][nt] = mfma_bf16(a1, bh[nt][1], accf[mt][nt]);
      }
      if (z < 2) {
        i32x4 axh = *(const i32x4*)(lds + 16384 + ra);
        i32x4 axl = *(const i32x4*)(lds + 24576 + ra);
#pragma unroll
        for (int nt = 0; nt < 2; ++nt) {
          acci[mt][nt] = mfma_i8(axh, bwl[nt], acci[mt][nt]);
          acci[mt][nt] = mfma_i8(axl, bw[nt], acci[mt][nt]);
        }
      }
    }
    __syncthreads();
  }

#pragma unroll
  for (int mt = 0; mt < 4; ++mt)
#pragma unroll
    for (int nt = 0; nt < 2; ++nt)
#pragma unroll
      for (int r = 0; r < 4; ++r) {
        long gm = m0 + wm * 64 + mt * 16 + lk * 4 + r;
        int e = n0 + wn * 32 + nt * 16 + lr;
        float v = accf[mt][nt][r] + bias[e];
        if (z < 2) v += (float)acci[mt][nt][r] * PS_QKV;
        if (z == 2) {
          long b = gm >> 11, s = gm & 2047;
          vt[(b * Dd + e) * (long)Ss + s] = f2h(v);
        } else {
          u16 hb = f2bf(v);
          float lo = v - bf2f(hb);
          long idx = gm * Dd + e;
          if (z == 0) {
            qh[idx] = hb;
            qh_i8[idx] = (u8)(clamp_i8(bf2f(hb), INV_HI) & 255);
            ql_i8[idx] = (u8)(clamp_i8(lo, INV_LO) & 255);
          } else {
            kh[idx] = hb;
            k_i8[idx] = (u8)(clamp_i8(v, INV_HI) & 255);
            kl_i8[idx] = (u8)(clamp_i8(lo, INV_LO) & 255);
          }
        }
      }
}

// ---------------------------------------------------------------- scores GEMM
// scores[b][i][j] = q[b,i,:] . k[b,j,:]
// block-tile 128(i) x 64(j); bf16 main + i8 corrections, fp32 out.
__global__ void __launch_bounds__(256) score_gemm(
    const u16* __restrict__ qh, const u8* __restrict__ qh_i8, const u8* __restrict__ ql_i8,
    const u16* __restrict__ kh, const u8* __restrict__ k_i8, const u8* __restrict__ kl_i8,
    float* __restrict__ scores) {
  __shared__ char lds[49152];
  const int tid = threadIdx.x;
  const int z = blockIdx.z;  // batch
  const long m0 = (long)blockIdx.y * 128;
  const int n0 = blockIdx.x * 64;
  const int wave = tid >> 6, lane = tid & 63;
  const int wm = wave >> 1, wn = wave & 1;
  const int lr = lane & 15, lk = lane >> 4;

  const char* qhc = (const char*)qh + (long)z * Ss * Dd * 2;
  const char* qhic = (const char*)qh_i8 + (long)z * Ss * Dd;
  const char* qlic = (const char*)ql_i8 + (long)z * Ss * Dd;
  const char* khc = (const char*)kh + (long)z * Ss * Dd * 2;
  const char* kic = (const char*)k_i8 + (long)z * Ss * Dd;
  const char* klic = (const char*)kl_i8 + (long)z * Ss * Dd;

  f32x4 accf[4][2] = {};
  i32x4 acci[4][2] = {};

  for (int k0 = 0; k0 < Dd; k0 += 64) {
    stageT<2>(qhc, m0, 2048, 2 * k0, lds + 0, tid);
    stageT<2>(qhc, m0, 2048, 2 * k0 + 64, lds + 8192, tid);
    stageT<2>(qhic, m0, 1024, k0, lds + 16384, tid);
    stageT<2>(qlic, m0, 1024, k0, lds + 24576, tid);
    stageT<1>(khc, n0, 2048, 2 * k0, lds + 32768, tid);
    stageT<1>(khc, n0, 2048, 2 * k0 + 64, lds + 36864, tid);
    stageT<1>(kic, n0, 1024, k0, lds + 40960, tid);
    stageT<1>(klic, n0, 1024, k0, lds + 45056, tid);
    __syncthreads();
    bf16x8 bh[2][2];
    i32x4 bk[2], bkl[2];
#pragma unroll
    for (int nt = 0; nt < 2; ++nt) {
      int rb = (wn * 32 + nt * 16 + lr) * 64 + lk * 16;
      bh[nt][0] = frag_ld(lds + 32768 + rb);
      bh[nt][1] = frag_ld(lds + 36864 + rb);
      bk[nt] = *(const i32x4*)(lds + 40960 + rb);
      bkl[nt] = *(const i32x4*)(lds + 45056 + rb);
    }
#pragma unroll
    for (int mt = 0; mt < 4; ++mt) {
      int ra = (wm * 64 + mt * 16 + lr) * 64 + lk * 16;
      bf16x8 a0 = frag_ld(lds + 0 + ra);
      bf16x8 a1 = frag_ld(lds + 8192 + ra);
      i32x4 aqh = *(const i32x4*)(lds + 16384 + ra);
      i32x4 aql = *(const i32x4*)(lds + 24576 + ra);
#pragma unroll
      for (int nt = 0; nt < 2; ++nt) {
        accf[mt][nt] = mfma_bf16(a0, bh[nt][0], accf[mt][nt]);
        accf[mt][nt] = mfma_bf16(a1, bh[nt][1], accf[mt][nt]);
        acci[mt][nt] = mfma_i8(aqh, bkl[nt], acci[mt][nt]);
        acci[mt][nt] = mfma_i8(aql, bk[nt], acci[mt][nt]);
      }
    }
    __syncthreads();
  }

  float* srow = scores + (long)z * Ss * Ss;
#pragma unroll
  for (int mt = 0; mt < 4; ++mt)
#pragma unroll
    for (int nt = 0; nt < 2; ++nt)
#pragma unroll
      for (int r = 0; r < 4; ++r) {
        long i = m0 + wm * 64 + mt * 16 + lk * 4 + r;
        int j = n0 + wn * 32 + nt * 16 + lr;
        srow[i * Ss + j] = accf[mt][nt][r] + (float)acci[mt][nt][r] * PS_SCORE;
      }
}

// ---------------------------------------------------------------- softmax
// one block per row; reads 2048 fp32, writes 2048 f16 P aliased over the
// row's first half (all reads complete before first barrier).
__global__ void __launch_bounds__(256) softmax_rows(float* __restrict__ scores) {
  const long r = blockIdx.x;
  float* row = scores + r * Ss;
  const int t = threadIdx.x;
  const int wave = t >> 6, lane = t & 63;
  f32x4 v0 = ((const f32x4*)row)[t * 2];
  f32x4 v1 = ((const f32x4*)row)[t * 2 + 1];
  float a[8];
#pragma unroll
  for (int j = 0; j < 4; ++j) { a[j] = v0[j]; a[4 + j] = v1[j]; }

  float m = a[0];
#pragma unroll
  for (int j = 1; j < 8; ++j) m = fmaxf(m, a[j]);
#pragma unroll
  for (int off = 32; off >= 1; off >>= 1) m = fmaxf(m, __shfl_xor(m, off));
  __shared__ float red[4];
  if (lane == 0) red[wave] = m;
  __syncthreads();
  m = fmaxf(fmaxf(red[0], red[1]), fmaxf(red[2], red[3]));

  float e[8];
  float s = 0.f;
#pragma unroll
  for (int j = 0; j < 8; ++j) { e[j] = __expf(a[j] - m); s += e[j]; }
#pragma unroll
  for (int off = 32; off >= 1; off >>= 1) s += __shfl_xor(s, off);
  __syncthreads();
  if (lane == 0) red[wave] = s;
  __syncthreads();
  s = red[0] + red[1] + red[2] + red[3];
  float inv = 1.0f / s;

  u16x8 pk;
#pragma unroll
  for (int j = 0; j < 8; ++j) pk[j] = f2h(e[j] * inv);
  ((u16x8*)row)[t] = pk;  // f16 P over first half of the fp32 row
}

// ---------------------------------------------------------------- PV GEMM
// out[b][i][e] = sum_j P[b][i][j] * vt[b][e][j]   (f16)
__global__ void __launch_bounds__(256) pv_gemm(const u16* __restrict__ P,
                                               const u16* __restrict__ vt,
                                               float* __restrict__ out) {
  __shared__ char lds[16384];  // A | B
  const int tid = threadIdx.x;
  const int z = blockIdx.z;  // batch
  const u16* A = P + (long)z * Ss * 4096;    // P rows aliased in fp32 rows: stride 4096 u16
  const u16* Bp = vt + (long)z * Dd * Ss;    // [1024][2048]
  const long m0 = (long)blockIdx.y * 128;
  const int n0 = blockIdx.x * 128;

  const int wave = tid >> 6, lane = tid & 63;
  const int wm = wave >> 1, wn = wave & 1;
  const int lr = lane & 15, lk = lane >> 4;

  f32x4 acc[4][4] = {};

  for (int k0 = 0; k0 < Ss; k0 += 32) {
    stage8k(A, m0, k0, 4096, lds + 0, tid);
    stage8k(Bp, n0, k0, Ss, lds + 8192, tid);
    __syncthreads();
    f16x8 af[4], bf[4];
#pragma unroll
    for (int i = 0; i < 4; ++i) {
      int ra = (wm * 64 + i * 16 + lr) * 64 + lk * 16;
      int rb = (wn * 64 + i * 16 + lr) * 64 + lk * 16;
      af[i] = frag_ld_h(lds + ra);
      bf[i] = frag_ld_h(lds + 8192 + rb);
    }
#pragma unroll
    for (int mt = 0; mt < 4; ++mt)
#pragma unroll
      for (int nt = 0; nt < 4; ++nt)
        acc[mt][nt] = __builtin_amdgcn_mfma_f32_16x16x32_f16(af[mt], bf[nt], acc[mt][nt], 0, 0, 0);
    __syncthreads();
  }

  float* orow = out + (long)z * Ss * Dd;
#pragma unroll
  for (int mt = 0; mt < 4; ++mt)
#pragma unroll
    for (int nt = 0; nt < 4; ++nt)
#pragma unroll
      for (int r = 0; r < 4; ++r) {
        long i = m0 + wm * 64 + mt * 16 + lk * 4 + r;
        int e = n0 + wn * 64 + nt * 16 + lr;
        orow[i * Dd + e] = acc[mt][nt][r];
      }
}

// ---------------------------------------------------------------- launch
extern "C" void kernel_launch(void* const* d_in, const int* in_sizes, int n_in,
                              void* d_out, int out_size, void* d_ws, size_t ws_size,
                              hipStream_t stream) {
  const float* x = (const float*)d_in[0];
  const float* Wq = (const float*)d_in[1];
  const float* bq = (const float*)d_in[2];
  const float* Wk = (const float*)d_in[3];
  const float* bk = (const float*)d_in[4];
  const float* Wv = (const float*)d_in[5];
  const float* bv = (const float*)d_in[6];
  float* out = (float*)d_out;

  // workspace carve (~156 MB)
  char* p = (char*)d_ws;
  float* scores = (float*)p;                // 64 MB (x-digit buffers aliased:
  u16* xh = (u16*)p;                        //   dead before scores written)
  u8* xh_i8 = (u8*)(p + 16777216);
  u8* xl_i8 = (u8*)(p + 25165824);
  p += 67108864;
  u16* qh = (u16*)p; p += 16777216;
  u8* qh_i8 = (u8*)p; p += 8388608;
  u8* ql_i8 = (u8*)p; p += 8388608;
  u16* kh = (u16*)p; p += 16777216;
  u8* k_i8 = (u8*)p; p += 8388608;
  u8* kl_i8 = (u8*)p; p += 8388608;
  u16* vt = (u16*)p; p += 16777216;
  u16* wqh = (u16*)p; p += 2097152;
  u16* wkh = (u16*)p; p += 2097152;
  u16* wvh = (u16*)p; p += 2097152;
  u8* wq_i8 = (u8*)p; p += 1048576;
  u8* wql_i8 = (u8*)p; p += 1048576;
  u8* wk_i8 = (u8*)p; p += 1048576;
  u8* wkl_i8 = (u8*)p; p += 1048576;
  u8* wv_i8 = (u8*)p; p += 1048576;
  u8* wvl_i8 = (u8*)p; p += 1048576;

  // 1. converts (x + 3 weights)
  convert_all<<<dim3(11264), dim3(256), 0, stream>>>(
      x, Wq, Wk, Wv, xh, xh_i8, xl_i8, wqh, wq_i8, wql_i8, wkh, wk_i8, wkl_i8,
      wvh, wv_i8, wvl_i8);

  // 2. QKV projection (128x64 tiles)
  qkv_gemm<<<dim3(Dd / 64, Mtot / 128, 3), dim3(256), 0, stream>>>(
      xh, xh_i8, xl_i8, wqh, wq_i8, wql_i8, wkh, wk_i8, wkl_i8, wvh,
      bq, bk, bv, qh, qh_i8, ql_i8, kh, k_i8, kl_i8, vt);

  // 3. scores = q k^T (128x64 tiles)
  score_gemm<<<dim3(Ss / 64, Ss / 128, Bb), dim3(256), 0, stream>>>(
      qh, qh_i8, ql_i8, kh, k_i8, kl_i8, scores);

  // 4. softmax rows (P f16 written in place)
  softmax_rows<<<dim3(Bb * Ss), dim3(256), 0, stream>>>(scores);

  // 5. out = P @ v
  pv_gemm<<<dim3(Dd / 128, Ss / 128, Bb), dim3(256), 0, stream>>>((const u16*)scores, vt, out);
}

// Round 5
// 418.372 us; speedup vs baseline: 1.0795x; 1.0795x over previous
//
#include <hip/hip_runtime.h>

// SelfAttention: B=4, S=2048, D=1024, fp32 in/out.
// q=x@Wq^T+bq, k=..., v=...; out = softmax(q k^T) @ v   (no 1/sqrt(d) scale)
//
// Precision plan:
//  - q/k projections: split-bf16 (hi+lo) 3-term fp32-emulated bf16 MFMA (R2
//    scheme, validated). Epilogue emits q/k as 2 i8 digits (s0=2^-4, s1=2^-11).
//  - scores: pure 2-digit i8 MFMA (16x16x64), exact integer accumulation in
//    3 i32 acc sets (d0d0, d0d1+d1d0, d1d1); requant err ~6.4e-3 rms only.
//  - v projection: single bf16 term, f16 out (transposed); PV GEMM in f16.
// NO in-place P aliasing: P has its own dense buffer (R4's post-timing
// divergence suspect removed).

#define Bb 4
#define Ss 2048
#define Dd 1024
#define Mtot 8192  // B*S

typedef __bf16 bf16x8 __attribute__((ext_vector_type(8)));
typedef _Float16 f16x8 __attribute__((ext_vector_type(8)));
typedef float f32x4 __attribute__((ext_vector_type(4)));
typedef int i32x4 __attribute__((ext_vector_type(4)));
typedef unsigned short u16;
typedef unsigned int u32;
typedef unsigned char u8;
typedef u16 u16x8 __attribute__((ext_vector_type(8)));
typedef u16 u16x4 __attribute__((ext_vector_type(4)));
typedef void __attribute__((address_space(1))) gvoid_t;
typedef void __attribute__((address_space(3))) svoid_t;

// digit scales (powers of two; products align exactly)
#define S0 0.0625f            // 2^-4
#define S1 4.8828125e-4f      // 2^-11
#define S00 3.90625e-3f       // 2^-8
#define S01 3.0517578125e-5f  // 2^-15
#define S11 2.384185791015625e-7f  // 2^-22

__device__ __forceinline__ void gl_lds16(const void* g, void* l) {
  __builtin_amdgcn_global_load_lds((gvoid_t*)g, (svoid_t*)l, 16, 0, 0);
}

__device__ __forceinline__ u16 f2bf(float f) {  // RNE float->bf16
  u32 u = __builtin_bit_cast(u32, f);
  u = (u + 0x7FFFu + ((u >> 16) & 1u)) >> 16;
  return (u16)u;
}
__device__ __forceinline__ float bf2f(u16 h) {
  u32 u = ((u32)h) << 16;
  return __builtin_bit_cast(float, u);
}
__device__ __forceinline__ u16 f2h(float f) {
  return __builtin_bit_cast(u16, (_Float16)f);
}
__device__ __forceinline__ bf16x8 frag_ld(const char* p) {
  u16x8 v = *(const u16x8*)p;
  return __builtin_bit_cast(bf16x8, v);
}
__device__ __forceinline__ f16x8 frag_ld_h(const char* p) {
  u16x8 v = *(const u16x8*)p;
  return __builtin_bit_cast(f16x8, v);
}
__device__ __forceinline__ f32x4 mfma_bf16(bf16x8 a, bf16x8 b, f32x4 c) {
  return __builtin_amdgcn_mfma_f32_16x16x32_bf16(a, b, c, 0, 0, 0);
}
__device__ __forceinline__ i32x4 mfma_i8(i32x4 a, i32x4 b, i32x4 c) {
  return __builtin_amdgcn_mfma_i32_16x16x64_i8(a, b, c, 0, 0, 0);
}

// stage a tile with 64-byte rows to LDS; ROUNDS*4 KB, linear row-major.
template <int ROUNDS>
__device__ __forceinline__ void stageT(const char* g, long row0, long ldb,
                                       long k0b, char* l, int tid) {
#pragma unroll
  for (int r = 0; r < ROUNDS; ++r) {
    int o = r * 4096 + tid * 16;
    int row = o >> 6;
    int col = o & 63;
    gl_lds16(g + (row0 + row) * ldb + k0b + col, l + o);
  }
}

// 128x32 u16 tile (8 KB)
__device__ __forceinline__ void stage8k(const u16* gbase, long row0, int k0, int ld,
                                        char* lds, int tid) {
  stageT<2>((const char*)gbase, row0, (long)ld * 2, (long)k0 * 2, lds, tid);
}

// ---------------------------------------------------------------- converts
// blocks [0,8192): x   [8192,9216): Wq   [9216,10240): Wk   [10240,11264): Wv
__global__ void __launch_bounds__(256) split_convert_all(
    const float* __restrict__ x, const float* __restrict__ Wq,
    const float* __restrict__ Wk, const float* __restrict__ Wv,
    u16* __restrict__ xhi, u16* __restrict__ xlo,
    u16* __restrict__ wqh, u16* __restrict__ wql,
    u16* __restrict__ wkh, u16* __restrict__ wkl,
    u16* __restrict__ wvh, u16* __restrict__ wvl) {
  long b = blockIdx.x;
  const float* src;
  u16 *hi, *lo;
  long i;
  if (b < 8192) {
    src = x; hi = xhi; lo = xlo;
    i = b * 256 + threadIdx.x;
  } else {
    int w = (int)((b - 8192) >> 10);
    src = (w == 0) ? Wq : (w == 1) ? Wk : Wv;
    hi = (w == 0) ? wqh : (w == 1) ? wkh : wvh;
    lo = (w == 0) ? wql : (w == 1) ? wkl : wvl;
    i = ((b - 8192) & 1023) * 256 + threadIdx.x;
  }
  f32x4 v = ((const f32x4*)src)[i];
  u16x4 h, l;
#pragma unroll
  for (int j = 0; j < 4; ++j) {
    u16 hh = f2bf(v[j]);
    h[j] = hh;
    l[j] = f2bf(v[j] - bf2f(hh));
  }
  ((u16x4*)hi)[i] = h;
  ((u16x4*)lo)[i] = l;
}

// ---------------------------------------------------------------- QKV GEMM
// R2 structure: 128x128 tile, 4 waves, split-bf16 3-term for z<2.
// z=0: q -> 2 i8 digits   z=1: k -> 2 i8 digits   z=2: v -> f16 transposed
__global__ void __launch_bounds__(256) qkv_gemm(
    const u16* __restrict__ xhi, const u16* __restrict__ xlo,
    const u16* __restrict__ wqh, const u16* __restrict__ wql,
    const u16* __restrict__ wkh, const u16* __restrict__ wkl,
    const u16* __restrict__ wvh,
    const float* __restrict__ bq, const float* __restrict__ bk,
    const float* __restrict__ bv,
    u8* __restrict__ q0, u8* __restrict__ q1,
    u8* __restrict__ kd0, u8* __restrict__ kd1,
    u16* __restrict__ vt) {
  __shared__ char lds[32768];  // Ahi | Alo | Bhi | Blo (8 KB each)
  const int tid = threadIdx.x;
  const int z = blockIdx.z;
  const u16* wh = (z == 0) ? wqh : (z == 1) ? wkh : wvh;
  const u16* wl = (z == 0) ? wql : wkl;  // unused for z==2
  const float* bias = (z == 0) ? bq : (z == 1) ? bk : bv;
  const long m0 = (long)blockIdx.y * 128;
  const int n0 = blockIdx.x * 128;

  const int wave = tid >> 6, lane = tid & 63;
  const int wm = wave >> 1, wn = wave & 1;
  const int lr = lane & 15, lk = lane >> 4;

  f32x4 acc[4][4] = {};

  for (int k0 = 0; k0 < Dd; k0 += 32) {
    stage8k(xhi, m0, k0, Dd, lds + 0, tid);
    stage8k(wh, n0, k0, Dd, lds + 16384, tid);
    if (z < 2) {
      stage8k(xlo, m0, k0, Dd, lds + 8192, tid);
      stage8k(wl, n0, k0, Dd, lds + 24576, tid);
    }
    __syncthreads();
    bf16x8 ah[4], al[4], bh[4], bl[4];
#pragma unroll
    for (int i = 0; i < 4; ++i) {
      int ra = (wm * 64 + i * 16 + lr) * 64 + lk * 16;
      int rb = (wn * 64 + i * 16 + lr) * 64 + lk * 16;
      ah[i] = frag_ld(lds + ra);
      bh[i] = frag_ld(lds + 16384 + rb);
      if (z < 2) {
        al[i] = frag_ld(lds + 8192 + ra);
        bl[i] = frag_ld(lds + 24576 + rb);
      }
    }
#pragma unroll
    for (int mt = 0; mt < 4; ++mt)
#pragma unroll
      for (int nt = 0; nt < 4; ++nt) {
        acc[mt][nt] = mfma_bf16(ah[mt], bh[nt], acc[mt][nt]);
        if (z < 2) {
          acc[mt][nt] = mfma_bf16(ah[mt], bl[nt], acc[mt][nt]);
          acc[mt][nt] = mfma_bf16(al[mt], bh[nt], acc[mt][nt]);
        }
      }
    __syncthreads();
  }

#pragma unroll
  for (int mt = 0; mt < 4; ++mt)
#pragma unroll
    for (int nt = 0; nt < 4; ++nt)
#pragma unroll
      for (int r = 0; r < 4; ++r) {
        long gm = m0 + wm * 64 + mt * 16 + lk * 4 + r;
        int e = n0 + wn * 64 + nt * 16 + lr;
        float v = acc[mt][nt][r] + bias[e];
        if (z == 2) {
          long b = gm >> 11, s = gm & 2047;
          vt[(b * Dd + e) * (long)Ss + s] = f2h(v);
        } else {
          int d0 = __float2int_rn(fminf(fmaxf(v * 16.f, -127.f), 127.f));
          float rres = v - (float)d0 * S0;
          int d1 = __float2int_rn(fminf(fmaxf(rres * 2048.f, -127.f), 127.f));
          long idx = gm * Dd + e;
          if (z == 0) {
            q0[idx] = (u8)d0;
            q1[idx] = (u8)d1;
          } else {
            kd0[idx] = (u8)d0;
            kd1[idx] = (u8)d1;
          }
        }
      }
}

// ---------------------------------------------------------------- scores GEMM
// scores[b][i][j] = q[b,i,:].k[b,j,:] via pure 2-digit i8 MFMA (exact int acc)
// 128x128 block, 4 waves (2x2), wave-tile 64x64. 32 KB LDS, K-64 steps.
__global__ void __launch_bounds__(256) score_gemm(
    const u8* __restrict__ q0, const u8* __restrict__ q1,
    const u8* __restrict__ kd0, const u8* __restrict__ kd1,
    float* __restrict__ scores) {
  __shared__ char lds[32768];  // q0 | q1 | k0 | k1 (8 KB each)
  const int tid = threadIdx.x;
  const int z = blockIdx.z;  // batch
  const long base = (long)z * Ss * Dd;
  const long m0 = (long)blockIdx.y * 128;
  const int n0 = blockIdx.x * 128;
  const int wave = tid >> 6, lane = tid & 63;
  const int wm = wave >> 1, wn = wave & 1;
  const int lr = lane & 15, lk = lane >> 4;

  i32x4 accM[4][4] = {};  // d0*d0   scale 2^-8
  i32x4 accX[4][4] = {};  // d0*d1 + d1*d0   scale 2^-15
  i32x4 accY[4][4] = {};  // d1*d1   scale 2^-22

  for (int kk = 0; kk < Dd; kk += 64) {
    stageT<2>((const char*)q0 + base, m0, Dd, kk, lds + 0, tid);
    stageT<2>((const char*)q1 + base, m0, Dd, kk, lds + 8192, tid);
    stageT<2>((const char*)kd0 + base, n0, Dd, kk, lds + 16384, tid);
    stageT<2>((const char*)kd1 + base, n0, Dd, kk, lds + 24576, tid);
    __syncthreads();
    i32x4 b0[4], b1[4];
#pragma unroll
    for (int nt = 0; nt < 4; ++nt) {
      int rb = (wn * 64 + nt * 16 + lr) * 64 + lk * 16;
      b0[nt] = *(const i32x4*)(lds + 16384 + rb);
      b1[nt] = *(const i32x4*)(lds + 24576 + rb);
    }
#pragma unroll
    for (int mt = 0; mt < 4; ++mt) {
      int ra = (wm * 64 + mt * 16 + lr) * 64 + lk * 16;
      i32x4 a0 = *(const i32x4*)(lds + 0 + ra);
      i32x4 a1 = *(const i32x4*)(lds + 8192 + ra);
#pragma unroll
      for (int nt = 0; nt < 4; ++nt) {
        accM[mt][nt] = mfma_i8(a0, b0[nt], accM[mt][nt]);
        accX[mt][nt] = mfma_i8(a0, b1[nt], accX[mt][nt]);
        accX[mt][nt] = mfma_i8(a1, b0[nt], accX[mt][nt]);
        accY[mt][nt] = mfma_i8(a1, b1[nt], accY[mt][nt]);
      }
    }
    __syncthreads();
  }

  float* srow = scores + (long)z * Ss * Ss;
#pragma unroll
  for (int mt = 0; mt < 4; ++mt)
#pragma unroll
    for (int nt = 0; nt < 4; ++nt)
#pragma unroll
      for (int r = 0; r < 4; ++r) {
        long i = m0 + wm * 64 + mt * 16 + lk * 4 + r;
        int j = n0 + wn * 64 + nt * 16 + lr;
        srow[i * Ss + j] = (float)accM[mt][nt][r] * S00 +
                           (float)accX[mt][nt][r] * S01 +
                           (float)accY[mt][nt][r] * S11;
      }
}

// ---------------------------------------------------------------- softmax
// one block per row; reads 2048 fp32 scores, writes 2048 f16 P to a
// SEPARATE dense buffer (stride 2048 u16). No in-place aliasing.
__global__ void __launch_bounds__(256) softmax_rows(const float* __restrict__ scores,
                                                    u16* __restrict__ P) {
  const long r = blockIdx.x;
  const float* row = scores + r * Ss;
  u16* prow = P + r * Ss;
  const int t = threadIdx.x;
  const int wave = t >> 6, lane = t & 63;
  f32x4 v0 = ((const f32x4*)row)[t * 2];
  f32x4 v1 = ((const f32x4*)row)[t * 2 + 1];
  float a[8];
#pragma unroll
  for (int j = 0; j < 4; ++j) { a[j] = v0[j]; a[4 + j] = v1[j]; }

  float m = a[0];
#pragma unroll
  for (int j = 1; j < 8; ++j) m = fmaxf(m, a[j]);
#pragma unroll
  for (int off = 32; off >= 1; off >>= 1) m = fmaxf(m, __shfl_xor(m, off));
  __shared__ float red[4];
  if (lane == 0) red[wave] = m;
  __syncthreads();
  m = fmaxf(fmaxf(red[0], red[1]), fmaxf(red[2], red[3]));

  float e[8];
  float s = 0.f;
#pragma unroll
  for (int j = 0; j < 8; ++j) { e[j] = __expf(a[j] - m); s += e[j]; }
#pragma unroll
  for (int off = 32; off >= 1; off >>= 1) s += __shfl_xor(s, off);
  __syncthreads();
  if (lane == 0) red[wave] = s;
  __syncthreads();
  s = red[0] + red[1] + red[2] + red[3];
  float inv = 1.0f / s;

  u16x8 pk;
#pragma unroll
  for (int j = 0; j < 8; ++j) pk[j] = f2h(e[j] * inv);
  ((u16x8*)prow)[t] = pk;
}

// ---------------------------------------------------------------- PV GEMM
// out[b][i][e] = sum_j P[b][i][j] * vt[b][e][j]   (f16, dense P)
__global__ void __launch_bounds__(256) pv_gemm(const u16* __restrict__ P,
                                               const u16* __restrict__ vt,
                                               float* __restrict__ out) {
  __shared__ char lds[16384];  // A | B
  const int tid = threadIdx.x;
  const int z = blockIdx.z;  // batch
  const u16* A = P + (long)z * Ss * Ss;    // dense [2048][2048] f16
  const u16* Bp = vt + (long)z * Dd * Ss;  // [1024][2048]
  const long m0 = (long)blockIdx.y * 128;
  const int n0 = blockIdx.x * 128;

  const int wave = tid >> 6, lane = tid & 63;
  const int wm = wave >> 1, wn = wave & 1;
  const int lr = lane & 15, lk = lane >> 4;

  f32x4 acc[4][4] = {};

  for (int k0 = 0; k0 < Ss; k0 += 32) {
    stage8k(A, m0, k0, Ss, lds + 0, tid);
    stage8k(Bp, n0, k0, Ss, lds + 8192, tid);
    __syncthreads();
    f16x8 af[4], bf[4];
#pragma unroll
    for (int i = 0; i < 4; ++i) {
      int ra = (wm * 64 + i * 16 + lr) * 64 + lk * 16;
      int rb = (wn * 64 + i * 16 + lr) * 64 + lk * 16;
      af[i] = frag_ld_h(lds + ra);
      bf[i] = frag_ld_h(lds + 8192 + rb);
    }
#pragma unroll
    for (int mt = 0; mt < 4; ++mt)
#pragma unroll
      for (int nt = 0; nt < 4; ++nt)
        acc[mt][nt] = __builtin_amdgcn_mfma_f32_16x16x32_f16(af[mt], bf[nt], acc[mt][nt], 0, 0, 0);
    __syncthreads();
  }

  float* orow = out + (long)z * Ss * Dd;
#pragma unroll
  for (int mt = 0; mt < 4; ++mt)
#pragma unroll
    for (int nt = 0; nt < 4; ++nt)
#pragma unroll
      for (int r = 0; r < 4; ++r) {
        long i = m0 + wm * 64 + mt * 16 + lk * 4 + r;
        int e = n0 + wn * 64 + nt * 16 + lr;
        orow[i * Dd + e] = acc[mt][nt][r];
      }
}

// ---------------------------------------------------------------- launch
extern "C" void kernel_launch(void* const* d_in, const int* in_sizes, int n_in,
                              void* d_out, int out_size, void* d_ws, size_t ws_size,
                              hipStream_t stream) {
  const float* x = (const float*)d_in[0];
  const float* Wq = (const float*)d_in[1];
  const float* bq = (const float*)d_in[2];
  const float* Wk = (const float*)d_in[3];
  const float* bk = (const float*)d_in[4];
  const float* Wv = (const float*)d_in[5];
  const float* bv = (const float*)d_in[6];
  float* out = (float*)d_out;

  // workspace carve (156 MiB, same footprint as passing R2)
  char* p = (char*)d_ws;
  float* scores = (float*)p;          // 64 MB; xhi/xlo aliased underneath
  u16* xhi = (u16*)p;                 //   (dead before scores written)
  u16* xlo = (u16*)(p + 16777216);
  p += 67108864;
  u8* q0 = (u8*)p; p += 8388608;
  u8* q1 = (u8*)p; p += 8388608;
  u8* kd0 = (u8*)p; p += 8388608;
  u8* kd1 = (u8*)p; p += 8388608;
  u16* Pbuf = (u16*)p; p += 33554432;  // dense f16 P [4][2048][2048]
  u16* vt = (u16*)p; p += 16777216;
  u16* wqh = (u16*)p; p += 2097152;
  u16* wql = (u16*)p; p += 2097152;
  u16* wkh = (u16*)p; p += 2097152;
  u16* wkl = (u16*)p; p += 2097152;
  u16* wvh = (u16*)p; p += 2097152;
  u16* wvl = (u16*)p; p += 2097152;

  // 1. split converts (x + 3 weights)
  split_convert_all<<<dim3(11264), dim3(256), 0, stream>>>(
      x, Wq, Wk, Wv, xhi, xlo, wqh, wql, wkh, wkl, wvh, wvl);

  // 2. QKV projection (q/k -> i8 digits, v -> f16 transposed)
  qkv_gemm<<<dim3(Dd / 128, Mtot / 128, 3), dim3(256), 0, stream>>>(
      xhi, xlo, wqh, wql, wkh, wkl, wvh, bq, bk, bv, q0, q1, kd0, kd1, vt);

  // 3. scores = q k^T (pure i8)
  score_gemm<<<dim3(Ss / 128, Ss / 128, Bb), dim3(256), 0, stream>>>(
      q0, q1, kd0, kd1, scores);

  // 4. softmax rows -> dense P
  softmax_rows<<<dim3(Bb * Ss), dim3(256), 0, stream>>>(scores, Pbuf);

  // 5. out = P @ v
  pv_gemm<<<dim3(Dd / 128, Ss / 128, Bb), dim3(256), 0, stream>>>(Pbuf, vt, out);
}